// Round 6
// baseline (239.743 us; speedup 1.0000x reference)
//
#include <hip/hip_runtime.h>
#include <stdint.h>

// x (8,3,40,128,128) f32, W (16,3,3,3,3) f32, b (16) f32.
// conv3d VALID -> softmax(C=16) -> 4x4x4 truncating maxpool -> (8,16,9,31,31).
//
// R6: swapped-operand MFMA (D[oc][pos] = W x X), no max-subtract softmax,
// channel-sum via 3 adds + ds_swizzle(^16) + ds_bpermute(^32), ds_read_b96
// x-gather with fully-unrolled 16 M-tiles (offsets fold into ds immediates),
// float2/ds_write_b64 staging with truncation hi/lo bf16 split.

typedef float  f4  __attribute__((ext_vector_type(4)));
typedef short  s8v __attribute__((ext_vector_type(8)));
typedef unsigned int u3v __attribute__((ext_vector_type(3)));

#define LOG2E 1.44269504088896340736f

__device__ __host__ inline uint32_t bf16rnd(float x) {
    uint32_t u = __float_as_uint(x);
    return (u + 0x7FFFu + ((u >> 16) & 1u)) >> 16;
}

// Weight-fragment table (same as R5): wd[(T*64+l)*4+r] = dup16(bf16(W[l&15][p]*log2e)),
// plane p = 4T + (l>>4) -> (ci,kd,kh), tap r = kw; 0 for p>=27 or r==3.
// Serves as MFMA *A* operand now: A[row=l&15=oc][k=(g,r)=(plane,kw)].
__global__ void build_bfrag(const float* __restrict__ W, uint32_t* __restrict__ wd) {
    int idx = blockIdx.x * 256 + threadIdx.x;       // 7*64*4 = 1792
    if (idx < 1792) {
        int r = idx & 3, l = (idx >> 2) & 63, T = idx >> 8;
        int p = 4 * T + (l >> 4), n = l & 15;
        uint32_t v = 0;
        if (p < 27 && r < 3) {
            int ci = p / 9, kd = (p / 3) % 3, kh = p % 3;
            float w = W[(((n * 3 + ci) * 3 + kd) * 3 + kh) * 3 + r] * LOG2E;
            uint32_t h = bf16rnd(w);
            v = (h << 16) | h;
        }
        wd[idx] = v;
    }
}

// truncation-based hi/lo bf16 split: exact to ~2^-16 relative (lo absorbs hi's
// truncation error). Weight bf16 rounding (2^-8) dominates the error budget.
__device__ inline uint32_t packhl(float v) {
    uint32_t u  = __float_as_uint(v);
    uint32_t hb = u >> 16;
    float    d  = v - __uint_as_float(u & 0xFFFF0000u);
    return (__float_as_uint(d) & 0xFFFF0000u) | hb;
}

template<int CTRL>
__device__ inline float dppf(float v) {
    return __int_as_float(__builtin_amdgcn_update_dpp(
        0, __float_as_int(v), CTRL, 0xF, 0xF, true));
}

__global__ __launch_bounds__(256, 4)
void conv_softmax_pool(const float* __restrict__ x,
                       const float* __restrict__ bias,
                       const uint32_t* __restrict__ wd,
                       float* __restrict__ out) {
    const int bid = blockIdx.x;
    const int wt  = bid & 1;            // w-tile: wo 0..15 / 16..30
    const int ho  = (bid >> 1) % 31;
    const int dpo = (bid / 62) % 9;
    const int b   = bid / 558;          // 558 = 2*31*9

    const int w0 = wt * 64;
    const int h0 = ho * 4;
    const int d0 = dpo * 4;

    __shared__ uint32_t xs[3 * 6 * 6 * 66];     // 28512 B, {lo<<16 | hi} pairs

    const int tid = threadIdx.x;

    // ---- stage x tile: float2 loads, b64 LDS writes ----
    const size_t xbase = (size_t)b * (3ull * 40 * 128 * 128);
    #pragma unroll 1
    for (int it = 0; it < 14; ++it) {
        int idx = tid + it * 256;                // pair units: 3*6*6*33 = 3564
        if (idx < 3564) {
            int pw = idx % 33;
            int t  = idx / 33;
            int h  = t % 6;  t /= 6;
            int d  = t % 6;
            int ci = t / 6;
            int gw = w0 + 2 * pw;
            float2 v = make_float2(0.0f, 0.0f);
            if (gw < 128)
                v = *(const float2*)&x[xbase + ((size_t)ci * 40 + (d0 + d)) * 16384
                                             + (size_t)(h0 + h) * 128 + gw];
            uint2 pkd = make_uint2(packhl(v.x), packhl(v.y));
            *(uint2*)&xs[(((ci * 6 + d) * 6 + h) * 66) + 2 * pw] = pkd;
        }
    }

    const int lane = tid & 63;
    const int wv   = tid >> 6;          // wave: positions w = w0 + 16wv + (lane&15)
    const int n    = lane & 15;         // MFMA col = position
    const int g    = lane >> 4;

    // weight A-fragments (per-lane VGPRs, same for all waves)
    s8v wA[7];
    {
        const uint4* wsp = (const uint4*)wd;
        #pragma unroll
        for (int T = 0; T < 7; ++T)
            wA[T] = __builtin_bit_cast(s8v, wsp[T * 64 + lane]);
    }
    // per-lane plane base pointers (pad plane clamped; its weights are 0)
    const uint32_t* tp[7];
    #pragma unroll
    for (int T = 0; T < 7; ++T) {
        int p = 4 * T + g; if (p > 26) p = 26;
        int ci = p / 9, kd = (p / 3) % 3, kh = p % 3;
        tp[T] = xs + ((ci * 6 + kd) * 6 + kh) * 66 + 16 * wv + n;
    }
    // bias for this lane's 4 oc rows (oc = 4g + r), pre-scaled by log2e
    float bl0, bl1, bl2, bl3;
    {
        float4 bv = ((const float4*)bias)[g];
        bl0 = bv.x * LOG2E; bl1 = bv.y * LOG2E;
        bl2 = bv.z * LOG2E; bl3 = bv.w * LOG2E;
    }
    const int bpaddr = ((lane ^ 32) << 2);      // ds_bpermute byte index

    __syncthreads();

    float pool0 = 0.0f, pool1 = 0.0f, pool2 = 0.0f, pool3 = 0.0f;

    #pragma unroll
    for (int dd = 0; dd < 4; ++dd) {
        #pragma unroll
        for (int hh = 0; hh < 4; ++hh) {
            const int off = (dd * 6 + hh) * 66;  // compile-time, folds into ds offset
            f4 acc = {bl0, bl1, bl2, bl3};
            #pragma unroll
            for (int T = 0; T < 7; ++T) {
                u3v xw = *(const u3v*)(tp[T] + off);   // ds_read_b96
                union { uint32_t u[4]; s8v s; } A;
                A.u[0] = xw.x; A.u[1] = xw.y; A.u[2] = xw.z; A.u[3] = 0;
                acc = __builtin_amdgcn_mfma_f32_16x16x32_bf16(wA[T], A.s, acc, 0, 0, 0);
            }
            // softmax over oc, no max-subtract (|logit*log2e| < ~6, exp2 safe)
            float e0 = __builtin_amdgcn_exp2f(acc[0]);
            float e1 = __builtin_amdgcn_exp2f(acc[1]);
            float e2 = __builtin_amdgcn_exp2f(acc[2]);
            float e3 = __builtin_amdgcn_exp2f(acc[3]);
            float s = (e0 + e1) + (e2 + e3);     // partial: this lane's 4 oc
            s += __int_as_float(__builtin_amdgcn_ds_swizzle(__float_as_int(s), 0x401F)); // ^16
            s += __int_as_float(__builtin_amdgcn_ds_bpermute(bpaddr, __float_as_int(s))); // ^32
            float inv = __builtin_amdgcn_rcpf(s);
            pool0 = fmaxf(pool0, e0 * inv);
            pool1 = fmaxf(pool1, e1 * inv);
            pool2 = fmaxf(pool2, e2 * inv);
            pool3 = fmaxf(pool3, e3 * inv);
        }
    }

    // w-pool over the 4 positions of each quad (positions n = 4q..4q+3)
    pool0 = fmaxf(pool0, dppf<0xB1>(pool0)); pool0 = fmaxf(pool0, dppf<0x4E>(pool0));
    pool1 = fmaxf(pool1, dppf<0xB1>(pool1)); pool1 = fmaxf(pool1, dppf<0x4E>(pool1));
    pool2 = fmaxf(pool2, dppf<0xB1>(pool2)); pool2 = fmaxf(pool2, dppf<0x4E>(pool2));
    pool3 = fmaxf(pool3, dppf<0xB1>(pool3)); pool3 = fmaxf(pool3, dppf<0x4E>(pool3));

    // lane picks reg r = lane&3: value for (oc = 4g + r, w-cell q = n>>2)
    {
        int r = lane & 3;
        float v01 = (r & 1) ? pool1 : pool0;
        float v23 = (r & 1) ? pool3 : pool2;
        float val = (r & 2) ? v23 : v01;
        int oc = 4 * g + r;
        int wo = wt * 16 + wv * 4 + (n >> 2);
        if (wo < 31)
            out[(((size_t)b * 16 + oc) * 9 + dpo) * 961
                + (size_t)ho * 31 + wo] = val;
    }
}

extern "C" void kernel_launch(void* const* d_in, const int* in_sizes, int n_in,
                              void* d_out, int out_size, void* d_ws, size_t ws_size,
                              hipStream_t stream) {
    const float* x  = (const float*)d_in[0];
    const float* W  = (const float*)d_in[1];
    const float* bb = (const float*)d_in[2];
    float* out = (float*)d_out;

    hipLaunchKernelGGL(build_bfrag, dim3(7), dim3(256), 0, stream,
                       W, (uint32_t*)d_ws);

    const int blocks = 8 * 9 * 31 * 2;  // 4464
    hipLaunchKernelGGL(conv_softmax_pool, dim3(blocks), dim3(256), 0, stream,
                       x, bb, (const uint32_t*)d_ws, out);
}

// Round 7
// 72.569 us; speedup vs baseline: 3.3036x; 3.3036x over previous
//
#include <hip/hip_runtime.h>
#include <stdint.h>

// x (8,3,40,128,128) f32, W (16,3,3,3,3) f32, b (16) f32.
// conv3d VALID -> softmax(C=16) -> 4x4x4 truncating maxpool -> (8,16,9,31,31).
//
// R7 = R5 skeleton (proven 111us schedule: D[pos][oc], DPP-only reductions,
// rolled dd/hh loops) minus the max-subtract (R6 proved raw exp2 is safe),
// plus truncation-based hi/lo staging and vectorized 3-dword gather.
// R6's LDS cross-lane softmax chain (ds_swizzle/bpermute + lgkmcnt waits)
// caused a 2.2x latency-serialization regression - reverted.

typedef float f4  __attribute__((ext_vector_type(4)));
typedef short s8v __attribute__((ext_vector_type(8)));
typedef unsigned int u3v __attribute__((ext_vector_type(3), aligned(4)));

#define LOG2E 1.44269504088896340736f

__device__ __host__ inline uint32_t bf16rnd(float x) {
    uint32_t u = __float_as_uint(x);
    return (u + 0x7FFFu + ((u >> 16) & 1u)) >> 16;
}

// B-fragment table: wd[(T*64+l)*4+r] = dup16(bf16(W[l&15][p][r]*log2e)),
// plane p = 4T + (l>>4) -> (ci,kd,kh), r = kw; 0 for p>=27 or r==3.
__global__ void build_bfrag(const float* __restrict__ W, uint32_t* __restrict__ wd) {
    int idx = blockIdx.x * 256 + threadIdx.x;       // 7*64*4 = 1792
    if (idx < 1792) {
        int r = idx & 3, l = (idx >> 2) & 63, T = idx >> 8;
        int p = 4 * T + (l >> 4), n = l & 15;
        uint32_t v = 0;
        if (p < 27 && r < 3) {
            int ci = p / 9, kd = (p / 3) % 3, kh = p % 3;
            float w = W[(((n * 3 + ci) * 3 + kd) * 3 + kh) * 3 + r] * LOG2E;
            uint32_t h = bf16rnd(w);
            v = (h << 16) | h;
        }
        wd[idx] = v;
    }
}

// truncation hi/lo split: hi = trunc16(v), lo = trunc16(v - hi); lo absorbs
// hi's truncation error, residual ~2^-16 relative. W's bf16 rounding dominates.
__device__ inline uint32_t packhl(float v) {
    uint32_t u  = __float_as_uint(v);
    uint32_t hb = u >> 16;
    float    d  = v - __uint_as_float(u & 0xFFFF0000u);
    return (__float_as_uint(d) & 0xFFFF0000u) | hb;
}

template<int CTRL>
__device__ inline float dppror(float v) {
    return __int_as_float(__builtin_amdgcn_update_dpp(
        0, __float_as_int(v), CTRL, 0xF, 0xF, true));
}
__device__ inline float allsum16(float v) {   // all-reduce add within 16-lane row
    v += dppror<0x121>(v);   // row_ror:1
    v += dppror<0x122>(v);   // row_ror:2
    v += dppror<0x124>(v);   // row_ror:4
    v += dppror<0x128>(v);   // row_ror:8
    return v;
}

__global__ __launch_bounds__(256, 4)
void conv_softmax_pool(const float* __restrict__ x,
                       const float* __restrict__ bias,
                       const uint32_t* __restrict__ wd,
                       float* __restrict__ out) {
    const int bid = blockIdx.x;
    const int wt  = bid & 1;            // w-tile: wo 0..15 / 16..30
    const int ho  = (bid >> 1) % 31;
    const int dpo = (bid / 62) % 9;
    const int b   = bid / 558;          // 558 = 2*31*9

    const int w0 = wt * 64;
    const int h0 = ho * 4;
    const int d0 = dpo * 4;

    __shared__ uint32_t xs[3 * 6 * 6 * 66];     // 28512 B, {lo<<16 | hi}

    const int tid = threadIdx.x;

    // ---- stage x tile: float2 loads, packed hi/lo, b64 LDS writes ----
    const size_t xbase = (size_t)b * (3ull * 40 * 128 * 128);
    #pragma unroll 1
    for (int it = 0; it < 14; ++it) {
        int idx = tid + it * 256;                // pair units: 3*6*6*33 = 3564
        if (idx < 3564) {
            int pw = idx % 33;
            int t  = idx / 33;
            int h  = t % 6;  t /= 6;
            int d  = t % 6;
            int ci = t / 6;
            int gw = w0 + 2 * pw;
            float2 v = make_float2(0.0f, 0.0f);
            if (gw < 128)
                v = *(const float2*)&x[xbase + ((size_t)ci * 40 + (d0 + d)) * 16384
                                             + (size_t)(h0 + h) * 128 + gw];
            uint2 pkd = make_uint2(packhl(v.x), packhl(v.y));
            *(uint2*)&xs[(((ci * 6 + d) * 6 + h) * 66) + 2 * pw] = pkd;
        }
    }

    const int lane = tid & 63;
    const int wv   = tid >> 6;          // wave: w positions [16wv, 16wv+16)
    const int m    = lane & 15;         // col = oc
    const int g    = lane >> 4;         // row group: rows 4g..4g+3 (= w-cell g)

    // weight B-fragments
    s8v bS[7];
    {
        const uint4* wsp = (const uint4*)wd;
        #pragma unroll
        for (int T = 0; T < 7; ++T)
            bS[T] = __builtin_bit_cast(s8v, wsp[T * 64 + lane]);
    }
    // per-lane static plane byte-offsets (pad plane clamped; its B entries = 0)
    uint32_t poff[7];
    #pragma unroll
    for (int T = 0; T < 7; ++T) {
        int p = 4 * T + g; if (p > 26) p = 26;
        int ci = p / 9, kd = (p / 3) % 3, kh = p % 3;
        poff[T] = (uint32_t)(((ci * 6 + kd) * 6 + kh) * 66) * 4u;
    }
    const float bl = bias[m] * LOG2E;   // acc cols are oc = m
    const char* xsb = (const char*)xs + (uint32_t)(16 * wv + m) * 4u;

    __syncthreads();

    float pool = 0.0f;
    #pragma unroll 1
    for (int dd = 0; dd < 4; ++dd) {
        #pragma unroll 1
        for (int hh = 0; hh < 4; ++hh) {
            const char* dhb = xsb + (uint32_t)((dd * 6 + hh) * 66) * 4u;
            f4 acc = {bl, bl, bl, bl};
            #pragma unroll
            for (int T = 0; T < 7; ++T) {
                u3v xw = *(const u3v*)(dhb + poff[T]);
                union { uint32_t u[4]; s8v s; } A;
                A.u[0] = xw.x; A.u[1] = xw.y; A.u[2] = xw.z; A.u[3] = 0;
                acc = __builtin_amdgcn_mfma_f32_16x16x32_bf16(A.s, bS[T], acc, 0, 0, 0);
            }
            // softmax over oc (16-lane rows), raw exp2 (|arg| < ~6, safe)
            float e0 = __builtin_amdgcn_exp2f(acc[0]);
            float e1 = __builtin_amdgcn_exp2f(acc[1]);
            float e2 = __builtin_amdgcn_exp2f(acc[2]);
            float e3 = __builtin_amdgcn_exp2f(acc[3]);
            float p0 = e0 * __builtin_amdgcn_rcpf(allsum16(e0));
            float p1 = e1 * __builtin_amdgcn_rcpf(allsum16(e1));
            float p2 = e2 * __builtin_amdgcn_rcpf(allsum16(e2));
            float p3 = e3 * __builtin_amdgcn_rcpf(allsum16(e3));
            // the 4 regs are w positions 4g..4g+3 = one pooled w-cell
            pool = fmaxf(pool, fmaxf(fmaxf(p0, p1), fmaxf(p2, p3)));
        }
    }

    // lane holds pooled value for (oc = m, w-cell = g)
    {
        int wo = wt * 16 + wv * 4 + g;
        if (wo < 31)
            out[(((size_t)b * 16 + m) * 9 + dpo) * 961
                + (size_t)ho * 31 + wo] = pool;
    }
}

extern "C" void kernel_launch(void* const* d_in, const int* in_sizes, int n_in,
                              void* d_out, int out_size, void* d_ws, size_t ws_size,
                              hipStream_t stream) {
    const float* x  = (const float*)d_in[0];
    const float* W  = (const float*)d_in[1];
    const float* bb = (const float*)d_in[2];
    float* out = (float*)d_out;

    hipLaunchKernelGGL(build_bfrag, dim3(7), dim3(256), 0, stream,
                       W, (uint32_t*)d_ws);

    const int blocks = 8 * 9 * 31 * 2;  // 4464
    hipLaunchKernelGGL(conv_softmax_pool, dim3(blocks), dim3(256), 0, stream,
                       x, bb, (const uint32_t*)d_ws, out);
}